// Round 7
// baseline (424.053 us; speedup 1.0000x reference)
//
#include <hip/hip_runtime.h>
#include <hip/hip_fp16.h>

// ---------------------------------------------------------------------------
// 3-layer GAT (heads=1) forward. N=100000, E=1600000, Ep=E+N, G=128,
// ND=16, ED=2, H=32.
// R7: k_agg gather loop 8-wide (was 4) + nontemporal rec load / xout store
// (keep h resident in L2 during the 218MB/layer gather storm).
// R6 structure otherwise unchanged: LDS bucket sort (256-node buckets),
// packed uint2 {src, half2(f0,f1)} edge records, commuted readout.
// ---------------------------------------------------------------------------

#define NBUCK_SHIFT 8
#define NBUCK_MAX 512
#define CAP 6144   // max staged edges per 256-node bucket (mean ~4350, max ~4650)

__global__ void k_node_enc(const float* __restrict__ nf, const float* __restrict__ W,
                           const float* __restrict__ b, float* __restrict__ x, int n) {
    int gid = blockIdx.x * 256 + threadIdx.x;
    if (gid >= n * 16) return;
    int node = gid >> 4, j = gid & 15;
    const float* xr = nf + node * 9;
    float acc = b[j];
#pragma unroll
    for (int k = 0; k < 9; ++k) acc += xr[k] * W[k * 16 + j];
    x[gid] = acc;
}

// Column sums of ef = ea@W_ee + b_ee (self-loop mean fill) without
// materializing ef. Per-wave partial to a unique slot (no atomics).
__global__ void k_colsum(const float4* __restrict__ ea4, const float* __restrict__ W,
                         const float* __restrict__ b, float2* __restrict__ partial, int e) {
    int tid = blockIdx.x * 256 + threadIdx.x;
    int e4 = e >> 2;
    float s0 = 0.f, s1 = 0.f;
    if (tid < e4) {
        float4 q0 = ea4[tid * 3], q1 = ea4[tid * 3 + 1], q2 = ea4[tid * 3 + 2];
        float a = q0.x + q0.w + q1.z + q2.y;
        float b2 = q0.y + q1.x + q1.w + q2.z;
        float c = q0.z + q1.y + q2.x + q2.w;
        s0 = a * W[0] + b2 * W[2] + c * W[4] + 4.f * b[0];
        s1 = a * W[1] + b2 * W[3] + c * W[5] + 4.f * b[1];
    }
#pragma unroll
    for (int off = 32; off > 0; off >>= 1) {
        s0 += __shfl_xor(s0, off, 64);
        s1 += __shfl_xor(s1, off, 64);
    }
    if ((threadIdx.x & 63) == 0)
        partial[(blockIdx.x << 2) + (threadIdx.x >> 6)] = make_float2(s0, s1);
}

// consts: [0..5]=(We@ae) per layer, [12..13]=self-loop mean fill
__global__ void k_consts(const float* __restrict__ We0, const float* __restrict__ ae0,
                         const float* __restrict__ We1, const float* __restrict__ ae1,
                         const float* __restrict__ We2, const float* __restrict__ ae2,
                         const float2* __restrict__ partial, int nw, float einv,
                         float* __restrict__ consts) {
    __shared__ float r0[256], r1[256];
    int t = threadIdx.x;
    float m0 = 0.f, m1 = 0.f;
    for (int i = t; i < nw; i += 256) {
        float2 v = partial[i];
        m0 += v.x; m1 += v.y;
    }
    r0[t] = m0; r1[t] = m1;
    __syncthreads();
    for (int o = 128; o > 0; o >>= 1) {
        if (t < o) { r0[t] += r0[t + o]; r1[t] += r1[t + o]; }
        __syncthreads();
    }
    if (t == 0) {
        consts[12] = r0[0] * einv;
        consts[13] = r1[0] * einv;
        const float* We[3] = {We0, We1, We2};
        const float* ae[3] = {ae0, ae1, ae2};
        for (int l = 0; l < 3; ++l) {
            float c0 = 0.f, c1 = 0.f;
            for (int j = 0; j < 32; ++j) {
                c0 += We[l][j] * ae[l][j];
                c1 += We[l][32 + j] * ae[l][j];
            }
            consts[l * 2 + 0] = c0;
            consts[l * 2 + 1] = c1;
        }
    }
}

// Phase A: bucket histogram (bucket = dst>>8). 4096 edges/block.
__global__ void k_hist(const int* __restrict__ ei1, int* __restrict__ bucket_cnt,
                       int e, int ep) {
    __shared__ int lh[NBUCK_MAX];
    int t = threadIdx.x;
    lh[t] = 0; lh[t + 256] = 0;
    __syncthreads();
    int base = blockIdx.x * 4096;
#pragma unroll
    for (int i = 0; i < 16; ++i) {
        int gid = base + i * 256 + t;
        if (gid < ep) {
            int d = (gid < e) ? ei1[gid] : gid - e;
            atomicAdd(&lh[d >> NBUCK_SHIFT], 1);
        }
    }
    __syncthreads();
    if (lh[t]) atomicAdd(&bucket_cnt[t], lh[t]);
    if (lh[t + 256]) atomicAdd(&bucket_cnt[t + 256], lh[t + 256]);
}

// Exclusive scan of bucket counts -> bases + cursors.
__global__ void __launch_bounds__(512)
k_bbase(const int* __restrict__ bucket_cnt, int* __restrict__ bucket_base,
        int* __restrict__ bcursor, int nbuck, int ep, int* __restrict__ rp, int n) {
    __shared__ int s[512];
    int t = threadIdx.x;
    int v = (t < nbuck) ? bucket_cnt[t] : 0;
    s[t] = v;
    __syncthreads();
    for (int o = 1; o < 512; o <<= 1) {
        int x = (t >= o) ? s[t - o] : 0;
        __syncthreads();
        s[t] += x;
        __syncthreads();
    }
    int ex = s[t] - v;
    if (t < nbuck) { bucket_base[t] = ex; bcursor[t] = ex; }
    if (t == 0) { bucket_base[nbuck] = ep; rp[n] = ep; }
}

// Phase B: stage edges grouped by bucket; one 8B uint2 {src<<8|dloc, half2}
// per edge; per-(block,bucket) run reservation keeps stores line-local.
__global__ void k_binB(const int* __restrict__ ei0, const int* __restrict__ ei1,
                       const float* __restrict__ ea, const float* __restrict__ We,
                       const float* __restrict__ be, const float* __restrict__ consts,
                       int* __restrict__ bcursor, uint2* __restrict__ st, int e, int ep) {
    __shared__ int lh[NBUCK_MAX], lcur[NBUCK_MAX];
    int t = threadIdx.x;
    lh[t] = 0; lh[t + 256] = 0;
    __syncthreads();
    int base = blockIdx.x * 4096;
    unsigned int sd[16], fh[16];
    int bk[16];
    float w00 = We[0], w10 = We[2], w20 = We[4];
    float w01 = We[1], w11 = We[3], w21 = We[5];
    float b0 = be[0], b1 = be[1];
#pragma unroll
    for (int i = 0; i < 16; ++i) {
        int gid = base + i * 256 + t;
        bk[i] = -1;
        if (gid < ep) {
            int s, d; float f0, f1;
            if (gid < e) {
                s = ei0[gid]; d = ei1[gid];
                const float* r = ea + (size_t)gid * 3;
                float a0 = r[0], a1 = r[1], a2 = r[2];
                f0 = a0 * w00 + a1 * w10 + a2 * w20 + b0;
                f1 = a0 * w01 + a1 * w11 + a2 * w21 + b1;
            } else {
                s = d = gid - e;
                f0 = consts[12]; f1 = consts[13];
            }
            bk[i] = d >> NBUCK_SHIFT;
            sd[i] = ((unsigned int)s << NBUCK_SHIFT) | (unsigned int)(d & 255);
            __half2 hh = __floats2half2_rn(f0, f1);
            fh[i] = *reinterpret_cast<unsigned int*>(&hh);
            atomicAdd(&lh[bk[i]], 1);
        }
    }
    __syncthreads();
    if (lh[t] > 0) lcur[t] = atomicAdd(&bcursor[t], lh[t]);
    if (lh[t + 256] > 0) lcur[t + 256] = atomicAdd(&bcursor[t + 256], lh[t + 256]);
    __syncthreads();
#pragma unroll
    for (int i = 0; i < 16; ++i) {
        if (bk[i] >= 0) {
            int pos = atomicAdd(&lcur[bk[i]], 1);
            st[pos] = make_uint2(sd[i], fh[i]);
        }
    }
}

// Phase C: one 512-thread block per bucket. LDS node-hist + scan -> rp
// coalesced; scatter into LDS-sorted buffer; stream out coalesced.
__global__ void __launch_bounds__(512)
k_binC(const uint2* __restrict__ st, const int* __restrict__ bucket_base,
       int* __restrict__ rp, uint2* __restrict__ rec, int n) {
    __shared__ int nh[256], ns[256];
    __shared__ uint2 rs[CAP];
    int k = blockIdx.x, t = threadIdx.x;
    int s0 = bucket_base[k], s1 = bucket_base[k + 1];
    int cnt = s1 - s0;
    if (t < 256) nh[t] = 0;
    __syncthreads();
    for (int i = s0 + t; i < s1; i += 512)
        atomicAdd(&nh[st[i].x & 255], 1);
    __syncthreads();
    if (t < 256) ns[t] = nh[t];
    __syncthreads();
    for (int o = 1; o < 256; o <<= 1) {
        int add = 0;
        if (t < 256 && t >= o) add = ns[t - o];
        __syncthreads();
        if (t < 256) ns[t] += add;
        __syncthreads();
    }
    int node0 = k << NBUCK_SHIFT;
    if (t < 256) {
        int startl = ns[t] - nh[t];      // exclusive, bucket-local
        if (node0 + t < n) rp[node0 + t] = s0 + startl;
        nh[t] = startl;                  // becomes local cursor
    }
    __syncthreads();
    for (int i = s0 + t; i < s1; i += 512) {
        uint2 v = st[i];
        int pos = atomicAdd(&nh[v.x & 255], 1);
        uint2 r = make_uint2(v.x >> NBUCK_SHIFT, v.y);
        if (pos < CAP) rs[pos] = r;
        else rec[s0 + pos] = r;          // overflow fallback (never in practice)
    }
    __syncthreads();
    int m = cnt < CAP ? cnt : CAP;
    for (int i = t; i < m; i += 512)
        rec[s0 + i] = rs[i];
}

template <int K>
__global__ void k_hproj(const float* __restrict__ x, const float* __restrict__ W,
                        const float* __restrict__ as_, const float* __restrict__ ad_,
                        float* __restrict__ h, float* __restrict__ asrc,
                        float* __restrict__ adst, int n) {
    __shared__ float sW[K * 32];
    for (int i = threadIdx.x; i < K * 32; i += 256) sW[i] = W[i];
    __syncthreads();
    int node = blockIdx.x * 8 + (threadIdx.x >> 5);
    int j = threadIdx.x & 31;
    if (node >= n) return;
    const float* xr = x + (size_t)node * K;
    float acc = 0.f;
#pragma unroll
    for (int k = 0; k < K; ++k) acc += xr[k] * sW[k * 32 + j];
    h[(size_t)node * 32 + j] = acc;
    float r1 = acc * as_[j], r2 = acc * ad_[j];
    for (int off = 16; off > 0; off >>= 1) {
        r1 += __shfl_xor(r1, off, 32);
        r2 += __shfl_xor(r2, off, 32);
    }
    if (j == 0) { asrc[node] = r1; adst[node] = r2; }
}

// Fused edge-softmax + aggregation. One 32-lane group per dst node.
// rec = {src, half2(f0,f1)}; 8-wide gather unroll; rec/xout nontemporal.
__global__ void k_agg(const int* __restrict__ rp, const uint2* __restrict__ rec,
                      const float* __restrict__ asrc, const float* __restrict__ adst,
                      const float* __restrict__ consts, const float* __restrict__ h,
                      const float* __restrict__ bb, float* __restrict__ xout,
                      int n, int layer) {
    int node = blockIdx.x * 8 + (threadIdx.x >> 5);
    int j = threadIdx.x & 31;
    if (node >= n) return;
    float c0 = consts[layer * 2], c1 = consts[layer * 2 + 1];
    int r0 = rp[node], r1 = rp[node + 1];
    float adn = adst[node];
    float acc = 0.f, psum = 0.f;
    for (int c = r0; c < r1; c += 32) {
        int i = c + j;
        float pe = 0.f; int s = 0;
        if (i < r1) {
            unsigned long long rv = __builtin_nontemporal_load(
                reinterpret_cast<const unsigned long long*>(rec + i));
            s = (int)(unsigned int)(rv & 0xffffffffull);
            unsigned int fv = (unsigned int)(rv >> 32);
            __half2 hh = *reinterpret_cast<__half2*>(&fv);
            float lg = asrc[s] + adn + __low2float(hh) * c0 + __high2float(hh) * c1;
            lg = lg > 0.f ? lg : 0.2f * lg;
            pe = __expf(lg);
        }
        psum += pe;
        int cnt = min(32, r1 - c);
        int t = 0;
        for (; t + 8 <= cnt; t += 8) {
            int s0 = __shfl(s, t, 32),     s1 = __shfl(s, t + 1, 32);
            int s2 = __shfl(s, t + 2, 32), s3 = __shfl(s, t + 3, 32);
            int s4 = __shfl(s, t + 4, 32), s5 = __shfl(s, t + 5, 32);
            int s6 = __shfl(s, t + 6, 32), s7 = __shfl(s, t + 7, 32);
            float p0 = __shfl(pe, t, 32),     p1 = __shfl(pe, t + 1, 32);
            float p2 = __shfl(pe, t + 2, 32), p3 = __shfl(pe, t + 3, 32);
            float p4 = __shfl(pe, t + 4, 32), p5 = __shfl(pe, t + 5, 32);
            float p6 = __shfl(pe, t + 6, 32), p7 = __shfl(pe, t + 7, 32);
            float h0 = h[(size_t)s0 * 32 + j];
            float h1 = h[(size_t)s1 * 32 + j];
            float h2 = h[(size_t)s2 * 32 + j];
            float h3 = h[(size_t)s3 * 32 + j];
            float h4 = h[(size_t)s4 * 32 + j];
            float h5 = h[(size_t)s5 * 32 + j];
            float h6 = h[(size_t)s6 * 32 + j];
            float h7 = h[(size_t)s7 * 32 + j];
            acc += p0 * h0; acc += p1 * h1; acc += p2 * h2; acc += p3 * h3;
            acc += p4 * h4; acc += p5 * h5; acc += p6 * h6; acc += p7 * h7;
        }
        for (; t + 4 <= cnt; t += 4) {
            int s0 = __shfl(s, t, 32),     s1 = __shfl(s, t + 1, 32);
            int s2 = __shfl(s, t + 2, 32), s3 = __shfl(s, t + 3, 32);
            float p0 = __shfl(pe, t, 32),     p1 = __shfl(pe, t + 1, 32);
            float p2 = __shfl(pe, t + 2, 32), p3 = __shfl(pe, t + 3, 32);
            float h0 = h[(size_t)s0 * 32 + j];
            float h1 = h[(size_t)s1 * 32 + j];
            float h2 = h[(size_t)s2 * 32 + j];
            float h3 = h[(size_t)s3 * 32 + j];
            acc += p0 * h0; acc += p1 * h1; acc += p2 * h2; acc += p3 * h3;
        }
        for (; t < cnt; ++t) {
            int st2 = __shfl(s, t, 32);
            float pt = __shfl(pe, t, 32);
            acc += pt * h[(size_t)st2 * 32 + j];
        }
    }
    for (int off = 16; off > 0; off >>= 1) psum += __shfl_xor(psum, off, 32);
    float res = acc / (psum + 1e-16f) + bb[j];
    __builtin_nontemporal_store(res, &xout[(size_t)node * 32 + j]);
}

__global__ void k_bounds(const int* __restrict__ batch, int* __restrict__ bounds,
                         int n, int g) {
    int t = blockIdx.x * 256 + threadIdx.x;
    if (t > g) return;
    if (t == g) { bounds[g] = n; return; }
    int lo = 0, hi = n;
    while (lo < hi) {
        int mid = (lo + hi) >> 1;
        if (batch[mid] < t) lo = mid + 1; else hi = mid;
    }
    bounds[t] = lo;
}

// out[g] = (1/cnt_g) * sum_{n in g} (x_cat[n] . W_l3) + b  -- commuted readout.
__global__ void k_dot(const float* __restrict__ x1, const float* __restrict__ x2,
                      const float* __restrict__ x3, const int* __restrict__ batch,
                      const float* __restrict__ Wl3, float* __restrict__ gsum, int n) {
    int node = blockIdx.x * 8 + (threadIdx.x >> 5);
    int j = threadIdx.x & 31;
    if (node >= n) return;
    size_t o = (size_t)node * 32 + j;
    float v = x1[o] * Wl3[j] + x2[o] * Wl3[32 + j] + x3[o] * Wl3[64 + j];
    for (int off = 16; off > 0; off >>= 1) v += __shfl_xor(v, off, 32);
    if (j == 0) atomicAdd(gsum + (size_t)batch[node] * 32 + (blockIdx.x & 31), v);
}

__global__ void k_out(const float* __restrict__ gsum, const int* __restrict__ bounds,
                      const float* __restrict__ bl3, float* __restrict__ out, int g) {
    int t = threadIdx.x;
    if (t >= g) return;
    float acc = 0.f;
    for (int k = 0; k < 32; ++k) acc += gsum[(size_t)t * 32 + k];
    float cnt = (float)(bounds[t + 1] - bounds[t]);
    out[t] = acc / fmaxf(cnt, 1.f) + bl3[0];
}

extern "C" void kernel_launch(void* const* d_in, const int* in_sizes, int n_in,
                              void* d_out, int out_size, void* d_ws, size_t ws_size,
                              hipStream_t stream) {
    (void)n_in; (void)out_size; (void)ws_size;
    const float* nf    = (const float*)d_in[0];
    const int*   ei    = (const int*)d_in[1];
    const float* ea    = (const float*)d_in[2];
    const int*   batch = (const int*)d_in[3];
    const float* W_ne  = (const float*)d_in[4];
    const float* b_ne  = (const float*)d_in[5];
    const float* W_ee  = (const float*)d_in[6];
    const float* b_ee  = (const float*)d_in[7];
    const float* W_l3  = (const float*)d_in[8];
    const float* b_l3  = (const float*)d_in[9];
    const float *Wl[3], *asl[3], *adl[3], *Wel[3], *ael[3], *bbl[3];
    for (int l = 0; l < 3; ++l) {
        Wl[l]  = (const float*)d_in[10 + 6 * l];
        asl[l] = (const float*)d_in[11 + 6 * l];
        adl[l] = (const float*)d_in[12 + 6 * l];
        Wel[l] = (const float*)d_in[13 + 6 * l];
        ael[l] = (const float*)d_in[14 + 6 * l];
        bbl[l] = (const float*)d_in[15 + 6 * l];
    }

    const int n  = in_sizes[3];        // 100000
    const int e  = in_sizes[2] / 3;    // 1600000
    const int ep = e + n;
    const int* ei0 = ei;
    const int* ei1 = ei + e;
    const int nbuck = (n + 255) >> NBUCK_SHIFT;   // 391

    char* w = (char*)d_ws;
    size_t off = 0;
    auto alloc = [&](size_t b) { size_t o = off; off = (off + b + 255) & ~(size_t)255; return o; };
    float*  x0      = (float*)(w + alloc((size_t)n * 16 * 4));
    float*  x1      = (float*)(w + alloc((size_t)n * 32 * 4));
    float*  x2      = (float*)(w + alloc((size_t)n * 32 * 4));
    float*  x3      = (float*)(w + alloc((size_t)n * 32 * 4));
    float*  h       = (float*)(w + alloc((size_t)n * 32 * 4));
    float*  asrc    = (float*)(w + alloc((size_t)n * 4));
    float*  adst    = (float*)(w + alloc((size_t)n * 4));
    uint2*  st      = (uint2*)(w + alloc((size_t)ep * 8));
    uint2*  rec     = (uint2*)(w + alloc((size_t)ep * 8));
    int*    rp      = (int*)(w + alloc((size_t)(n + 1) * 4));
    int*    bcnt    = (int*)(w + alloc(NBUCK_MAX * 4));
    int*    bbase   = (int*)(w + alloc((NBUCK_MAX + 1) * 4));
    int*    bcur    = (int*)(w + alloc(NBUCK_MAX * 4));
    float2* partial = (float2*)(w + alloc((size_t)8192 * 8));
    float*  consts  = (float*)(w + alloc(256));
    int*    bounds  = (int*)(w + alloc(129 * 4));
    float*  gsum    = (float*)(w + alloc((size_t)128 * 32 * 4));

    hipMemsetAsync(bcnt, 0, NBUCK_MAX * 4, stream);
    hipMemsetAsync(gsum, 0, (size_t)128 * 32 * 4, stream);

    int e4 = e >> 2;
    int nbe = (e4 + 255) / 256;
    int nw  = nbe * 4;
    int nbs = (ep + 4095) / 4096;

    k_node_enc<<<(n * 16 + 255) / 256, 256, 0, stream>>>(nf, W_ne, b_ne, x0, n);
    k_colsum<<<nbe, 256, 0, stream>>>((const float4*)ea, W_ee, b_ee, partial, e);
    k_consts<<<1, 256, 0, stream>>>(Wel[0], ael[0], Wel[1], ael[1], Wel[2], ael[2],
                                    partial, nw, 1.0f / (float)e, consts);
    k_hist<<<nbs, 256, 0, stream>>>(ei1, bcnt, e, ep);
    k_bbase<<<1, 512, 0, stream>>>(bcnt, bbase, bcur, nbuck, ep, rp, n);
    k_binB<<<nbs, 256, 0, stream>>>(ei0, ei1, ea, W_ee, b_ee, consts, bcur, st, e, ep);
    k_binC<<<nbuck, 512, 0, stream>>>(st, bbase, rp, rec, n);
    k_bounds<<<1, 256, 0, stream>>>(batch, bounds, n, 128);

    const float* xin = x0;
    float* xo[3] = {x1, x2, x3};
    for (int l = 0; l < 3; ++l) {
        if (l == 0)
            k_hproj<16><<<(n + 7) / 8, 256, 0, stream>>>(xin, Wl[l], asl[l], adl[l],
                                                         h, asrc, adst, n);
        else
            k_hproj<32><<<(n + 7) / 8, 256, 0, stream>>>(xin, Wl[l], asl[l], adl[l],
                                                         h, asrc, adst, n);
        k_agg<<<(n + 7) / 8, 256, 0, stream>>>(rp, rec, asrc, adst, consts,
                                               h, bbl[l], xo[l], n, l);
        xin = xo[l];
    }
    k_dot<<<(n + 7) / 8, 256, 0, stream>>>(x1, x2, x3, batch, W_l3, gsum, n);
    k_out<<<1, 128, 0, stream>>>(gsum, bounds, b_l3, (float*)d_out, 128);
}

// Round 8
// 417.746 us; speedup vs baseline: 1.0151x; 1.0151x over previous
//
#include <hip/hip_runtime.h>
#include <hip/hip_fp16.h>

// ---------------------------------------------------------------------------
// 3-layer GAT (heads=1) forward. N=100000, E=1600000, Ep=E+N, G=128,
// ND=16, ED=2, H=32.
// R8: h stored as packed half2 (6.4MB instead of 12.8MB). k_agg's fetch floor
// is ~8 XCDs x |h| (random src -> every XCD pulls the whole table into its
// private L2); fp16 halves that dominant term. asrc/adst still fp32 (computed
// from fp32 acc pre-rounding). NT store on xout reverted (R7 regression:
// next hproj re-reads it); NT load on rec kept (single-use stream).
// ---------------------------------------------------------------------------

#define NBUCK_SHIFT 8
#define NBUCK_MAX 512
#define CAP 6144   // max staged edges per 256-node bucket (mean ~4350, max ~4650)

__global__ void k_node_enc(const float* __restrict__ nf, const float* __restrict__ W,
                           const float* __restrict__ b, float* __restrict__ x, int n) {
    int gid = blockIdx.x * 256 + threadIdx.x;
    if (gid >= n * 16) return;
    int node = gid >> 4, j = gid & 15;
    const float* xr = nf + node * 9;
    float acc = b[j];
#pragma unroll
    for (int k = 0; k < 9; ++k) acc += xr[k] * W[k * 16 + j];
    x[gid] = acc;
}

// Column sums of ef = ea@W_ee + b_ee (self-loop mean fill) without
// materializing ef. Per-wave partial to a unique slot (no atomics).
__global__ void k_colsum(const float4* __restrict__ ea4, const float* __restrict__ W,
                         const float* __restrict__ b, float2* __restrict__ partial, int e) {
    int tid = blockIdx.x * 256 + threadIdx.x;
    int e4 = e >> 2;
    float s0 = 0.f, s1 = 0.f;
    if (tid < e4) {
        float4 q0 = ea4[tid * 3], q1 = ea4[tid * 3 + 1], q2 = ea4[tid * 3 + 2];
        float a = q0.x + q0.w + q1.z + q2.y;
        float b2 = q0.y + q1.x + q1.w + q2.z;
        float c = q0.z + q1.y + q2.x + q2.w;
        s0 = a * W[0] + b2 * W[2] + c * W[4] + 4.f * b[0];
        s1 = a * W[1] + b2 * W[3] + c * W[5] + 4.f * b[1];
    }
#pragma unroll
    for (int off = 32; off > 0; off >>= 1) {
        s0 += __shfl_xor(s0, off, 64);
        s1 += __shfl_xor(s1, off, 64);
    }
    if ((threadIdx.x & 63) == 0)
        partial[(blockIdx.x << 2) + (threadIdx.x >> 6)] = make_float2(s0, s1);
}

// consts: [0..5]=(We@ae) per layer, [12..13]=self-loop mean fill
__global__ void k_consts(const float* __restrict__ We0, const float* __restrict__ ae0,
                         const float* __restrict__ We1, const float* __restrict__ ae1,
                         const float* __restrict__ We2, const float* __restrict__ ae2,
                         const float2* __restrict__ partial, int nw, float einv,
                         float* __restrict__ consts) {
    __shared__ float r0[256], r1[256];
    int t = threadIdx.x;
    float m0 = 0.f, m1 = 0.f;
    for (int i = t; i < nw; i += 256) {
        float2 v = partial[i];
        m0 += v.x; m1 += v.y;
    }
    r0[t] = m0; r1[t] = m1;
    __syncthreads();
    for (int o = 128; o > 0; o >>= 1) {
        if (t < o) { r0[t] += r0[t + o]; r1[t] += r1[t + o]; }
        __syncthreads();
    }
    if (t == 0) {
        consts[12] = r0[0] * einv;
        consts[13] = r1[0] * einv;
        const float* We[3] = {We0, We1, We2};
        const float* ae[3] = {ae0, ae1, ae2};
        for (int l = 0; l < 3; ++l) {
            float c0 = 0.f, c1 = 0.f;
            for (int j = 0; j < 32; ++j) {
                c0 += We[l][j] * ae[l][j];
                c1 += We[l][32 + j] * ae[l][j];
            }
            consts[l * 2 + 0] = c0;
            consts[l * 2 + 1] = c1;
        }
    }
}

// Phase A: bucket histogram (bucket = dst>>8). 4096 edges/block.
__global__ void k_hist(const int* __restrict__ ei1, int* __restrict__ bucket_cnt,
                       int e, int ep) {
    __shared__ int lh[NBUCK_MAX];
    int t = threadIdx.x;
    lh[t] = 0; lh[t + 256] = 0;
    __syncthreads();
    int base = blockIdx.x * 4096;
#pragma unroll
    for (int i = 0; i < 16; ++i) {
        int gid = base + i * 256 + t;
        if (gid < ep) {
            int d = (gid < e) ? ei1[gid] : gid - e;
            atomicAdd(&lh[d >> NBUCK_SHIFT], 1);
        }
    }
    __syncthreads();
    if (lh[t]) atomicAdd(&bucket_cnt[t], lh[t]);
    if (lh[t + 256]) atomicAdd(&bucket_cnt[t + 256], lh[t + 256]);
}

// Exclusive scan of bucket counts -> bases + cursors.
__global__ void __launch_bounds__(512)
k_bbase(const int* __restrict__ bucket_cnt, int* __restrict__ bucket_base,
        int* __restrict__ bcursor, int nbuck, int ep, int* __restrict__ rp, int n) {
    __shared__ int s[512];
    int t = threadIdx.x;
    int v = (t < nbuck) ? bucket_cnt[t] : 0;
    s[t] = v;
    __syncthreads();
    for (int o = 1; o < 512; o <<= 1) {
        int x = (t >= o) ? s[t - o] : 0;
        __syncthreads();
        s[t] += x;
        __syncthreads();
    }
    int ex = s[t] - v;
    if (t < nbuck) { bucket_base[t] = ex; bcursor[t] = ex; }
    if (t == 0) { bucket_base[nbuck] = ep; rp[n] = ep; }
}

// Phase B: stage edges grouped by bucket; one 8B uint2 {src<<8|dloc, half2}
// per edge; per-(block,bucket) run reservation keeps stores line-local.
__global__ void k_binB(const int* __restrict__ ei0, const int* __restrict__ ei1,
                       const float* __restrict__ ea, const float* __restrict__ We,
                       const float* __restrict__ be, const float* __restrict__ consts,
                       int* __restrict__ bcursor, uint2* __restrict__ st, int e, int ep) {
    __shared__ int lh[NBUCK_MAX], lcur[NBUCK_MAX];
    int t = threadIdx.x;
    lh[t] = 0; lh[t + 256] = 0;
    __syncthreads();
    int base = blockIdx.x * 4096;
    unsigned int sd[16], fh[16];
    int bk[16];
    float w00 = We[0], w10 = We[2], w20 = We[4];
    float w01 = We[1], w11 = We[3], w21 = We[5];
    float b0 = be[0], b1 = be[1];
#pragma unroll
    for (int i = 0; i < 16; ++i) {
        int gid = base + i * 256 + t;
        bk[i] = -1;
        if (gid < ep) {
            int s, d; float f0, f1;
            if (gid < e) {
                s = ei0[gid]; d = ei1[gid];
                const float* r = ea + (size_t)gid * 3;
                float a0 = r[0], a1 = r[1], a2 = r[2];
                f0 = a0 * w00 + a1 * w10 + a2 * w20 + b0;
                f1 = a0 * w01 + a1 * w11 + a2 * w21 + b1;
            } else {
                s = d = gid - e;
                f0 = consts[12]; f1 = consts[13];
            }
            bk[i] = d >> NBUCK_SHIFT;
            sd[i] = ((unsigned int)s << NBUCK_SHIFT) | (unsigned int)(d & 255);
            __half2 hh = __floats2half2_rn(f0, f1);
            fh[i] = *reinterpret_cast<unsigned int*>(&hh);
            atomicAdd(&lh[bk[i]], 1);
        }
    }
    __syncthreads();
    if (lh[t] > 0) lcur[t] = atomicAdd(&bcursor[t], lh[t]);
    if (lh[t + 256] > 0) lcur[t + 256] = atomicAdd(&bcursor[t + 256], lh[t + 256]);
    __syncthreads();
#pragma unroll
    for (int i = 0; i < 16; ++i) {
        if (bk[i] >= 0) {
            int pos = atomicAdd(&lcur[bk[i]], 1);
            st[pos] = make_uint2(sd[i], fh[i]);
        }
    }
}

// Phase C: one 512-thread block per bucket. LDS node-hist + scan -> rp
// coalesced; scatter into LDS-sorted buffer; stream out coalesced.
__global__ void __launch_bounds__(512)
k_binC(const uint2* __restrict__ st, const int* __restrict__ bucket_base,
       int* __restrict__ rp, uint2* __restrict__ rec, int n) {
    __shared__ int nh[256], ns[256];
    __shared__ uint2 rs[CAP];
    int k = blockIdx.x, t = threadIdx.x;
    int s0 = bucket_base[k], s1 = bucket_base[k + 1];
    int cnt = s1 - s0;
    if (t < 256) nh[t] = 0;
    __syncthreads();
    for (int i = s0 + t; i < s1; i += 512)
        atomicAdd(&nh[st[i].x & 255], 1);
    __syncthreads();
    if (t < 256) ns[t] = nh[t];
    __syncthreads();
    for (int o = 1; o < 256; o <<= 1) {
        int add = 0;
        if (t < 256 && t >= o) add = ns[t - o];
        __syncthreads();
        if (t < 256) ns[t] += add;
        __syncthreads();
    }
    int node0 = k << NBUCK_SHIFT;
    if (t < 256) {
        int startl = ns[t] - nh[t];      // exclusive, bucket-local
        if (node0 + t < n) rp[node0 + t] = s0 + startl;
        nh[t] = startl;                  // becomes local cursor
    }
    __syncthreads();
    for (int i = s0 + t; i < s1; i += 512) {
        uint2 v = st[i];
        int pos = atomicAdd(&nh[v.x & 255], 1);
        uint2 r = make_uint2(v.x >> NBUCK_SHIFT, v.y);
        if (pos < CAP) rs[pos] = r;
        else rec[s0 + pos] = r;          // overflow fallback (never in practice)
    }
    __syncthreads();
    int m = cnt < CAP ? cnt : CAP;
    for (int i = t; i < m; i += 512)
        rec[s0 + i] = rs[i];
}

// h stored packed half2: h2[node*16 + (j>>1)] holds cols (2k, 2k+1).
template <int K>
__global__ void k_hproj(const float* __restrict__ x, const float* __restrict__ W,
                        const float* __restrict__ as_, const float* __restrict__ ad_,
                        unsigned int* __restrict__ h2, float* __restrict__ asrc,
                        float* __restrict__ adst, int n) {
    __shared__ float sW[K * 32];
    for (int i = threadIdx.x; i < K * 32; i += 256) sW[i] = W[i];
    __syncthreads();
    int node = blockIdx.x * 8 + (threadIdx.x >> 5);
    int j = threadIdx.x & 31;
    if (node >= n) return;
    const float* xr = x + (size_t)node * K;
    float acc = 0.f;
#pragma unroll
    for (int k = 0; k < K; ++k) acc += xr[k] * sW[k * 32 + j];
    float accp = __shfl_down(acc, 1, 32);
    if ((j & 1) == 0) {
        __half2 hh = __floats2half2_rn(acc, accp);
        h2[(size_t)node * 16 + (j >> 1)] = *reinterpret_cast<unsigned int*>(&hh);
    }
    float r1 = acc * as_[j], r2 = acc * ad_[j];
    for (int off = 16; off > 0; off >>= 1) {
        r1 += __shfl_xor(r1, off, 32);
        r2 += __shfl_xor(r2, off, 32);
    }
    if (j == 0) { asrc[node] = r1; adst[node] = r2; }
}

__device__ __forceinline__ float h2_get(const unsigned int* __restrict__ h2,
                                        int s, int word, bool hi) {
    unsigned int hw = h2[(size_t)s * 16 + word];
    __half2 hh = *reinterpret_cast<__half2*>(&hw);
    return hi ? __high2float(hh) : __low2float(hh);
}

// Fused edge-softmax + aggregation. One 32-lane group per dst node.
// rec = {src, half2(f0,f1)}; 8-wide gather unroll; rec NT load; h in fp16.
__global__ void k_agg(const int* __restrict__ rp, const uint2* __restrict__ rec,
                      const float* __restrict__ asrc, const float* __restrict__ adst,
                      const float* __restrict__ consts, const unsigned int* __restrict__ h2,
                      const float* __restrict__ bb, float* __restrict__ xout,
                      int n, int layer) {
    int node = blockIdx.x * 8 + (threadIdx.x >> 5);
    int j = threadIdx.x & 31;
    if (node >= n) return;
    float c0 = consts[layer * 2], c1 = consts[layer * 2 + 1];
    int r0 = rp[node], r1 = rp[node + 1];
    float adn = adst[node];
    int word = j >> 1;
    bool hi = (j & 1) != 0;
    float acc = 0.f, psum = 0.f;
    for (int c = r0; c < r1; c += 32) {
        int i = c + j;
        float pe = 0.f; int s = 0;
        if (i < r1) {
            unsigned long long rv = __builtin_nontemporal_load(
                reinterpret_cast<const unsigned long long*>(rec + i));
            s = (int)(unsigned int)(rv & 0xffffffffull);
            unsigned int fv = (unsigned int)(rv >> 32);
            __half2 hh = *reinterpret_cast<__half2*>(&fv);
            float lg = asrc[s] + adn + __low2float(hh) * c0 + __high2float(hh) * c1;
            lg = lg > 0.f ? lg : 0.2f * lg;
            pe = __expf(lg);
        }
        psum += pe;
        int cnt = min(32, r1 - c);
        int t = 0;
        for (; t + 8 <= cnt; t += 8) {
            int s0 = __shfl(s, t, 32),     s1 = __shfl(s, t + 1, 32);
            int s2 = __shfl(s, t + 2, 32), s3 = __shfl(s, t + 3, 32);
            int s4 = __shfl(s, t + 4, 32), s5 = __shfl(s, t + 5, 32);
            int s6 = __shfl(s, t + 6, 32), s7 = __shfl(s, t + 7, 32);
            float p0 = __shfl(pe, t, 32),     p1 = __shfl(pe, t + 1, 32);
            float p2 = __shfl(pe, t + 2, 32), p3 = __shfl(pe, t + 3, 32);
            float p4 = __shfl(pe, t + 4, 32), p5 = __shfl(pe, t + 5, 32);
            float p6 = __shfl(pe, t + 6, 32), p7 = __shfl(pe, t + 7, 32);
            float h0 = h2_get(h2, s0, word, hi);
            float h1 = h2_get(h2, s1, word, hi);
            float h2v = h2_get(h2, s2, word, hi);
            float h3 = h2_get(h2, s3, word, hi);
            float h4 = h2_get(h2, s4, word, hi);
            float h5 = h2_get(h2, s5, word, hi);
            float h6 = h2_get(h2, s6, word, hi);
            float h7 = h2_get(h2, s7, word, hi);
            acc += p0 * h0; acc += p1 * h1; acc += p2 * h2v; acc += p3 * h3;
            acc += p4 * h4; acc += p5 * h5; acc += p6 * h6; acc += p7 * h7;
        }
        for (; t + 4 <= cnt; t += 4) {
            int s0 = __shfl(s, t, 32),     s1 = __shfl(s, t + 1, 32);
            int s2 = __shfl(s, t + 2, 32), s3 = __shfl(s, t + 3, 32);
            float p0 = __shfl(pe, t, 32),     p1 = __shfl(pe, t + 1, 32);
            float p2 = __shfl(pe, t + 2, 32), p3 = __shfl(pe, t + 3, 32);
            float h0 = h2_get(h2, s0, word, hi);
            float h1 = h2_get(h2, s1, word, hi);
            float h2v = h2_get(h2, s2, word, hi);
            float h3 = h2_get(h2, s3, word, hi);
            acc += p0 * h0; acc += p1 * h1; acc += p2 * h2v; acc += p3 * h3;
        }
        for (; t < cnt; ++t) {
            int st2 = __shfl(s, t, 32);
            float pt = __shfl(pe, t, 32);
            acc += pt * h2_get(h2, st2, word, hi);
        }
    }
    for (int off = 16; off > 0; off >>= 1) psum += __shfl_xor(psum, off, 32);
    xout[(size_t)node * 32 + j] = acc / (psum + 1e-16f) + bb[j];
}

__global__ void k_bounds(const int* __restrict__ batch, int* __restrict__ bounds,
                         int n, int g) {
    int t = blockIdx.x * 256 + threadIdx.x;
    if (t > g) return;
    if (t == g) { bounds[g] = n; return; }
    int lo = 0, hi = n;
    while (lo < hi) {
        int mid = (lo + hi) >> 1;
        if (batch[mid] < t) lo = mid + 1; else hi = mid;
    }
    bounds[t] = lo;
}

// out[g] = (1/cnt_g) * sum_{n in g} (x_cat[n] . W_l3) + b  -- commuted readout.
__global__ void k_dot(const float* __restrict__ x1, const float* __restrict__ x2,
                      const float* __restrict__ x3, const int* __restrict__ batch,
                      const float* __restrict__ Wl3, float* __restrict__ gsum, int n) {
    int node = blockIdx.x * 8 + (threadIdx.x >> 5);
    int j = threadIdx.x & 31;
    if (node >= n) return;
    size_t o = (size_t)node * 32 + j;
    float v = x1[o] * Wl3[j] + x2[o] * Wl3[32 + j] + x3[o] * Wl3[64 + j];
    for (int off = 16; off > 0; off >>= 1) v += __shfl_xor(v, off, 32);
    if (j == 0) atomicAdd(gsum + (size_t)batch[node] * 32 + (blockIdx.x & 31), v);
}

__global__ void k_out(const float* __restrict__ gsum, const int* __restrict__ bounds,
                      const float* __restrict__ bl3, float* __restrict__ out, int g) {
    int t = threadIdx.x;
    if (t >= g) return;
    float acc = 0.f;
    for (int k = 0; k < 32; ++k) acc += gsum[(size_t)t * 32 + k];
    float cnt = (float)(bounds[t + 1] - bounds[t]);
    out[t] = acc / fmaxf(cnt, 1.f) + bl3[0];
}

extern "C" void kernel_launch(void* const* d_in, const int* in_sizes, int n_in,
                              void* d_out, int out_size, void* d_ws, size_t ws_size,
                              hipStream_t stream) {
    (void)n_in; (void)out_size; (void)ws_size;
    const float* nf    = (const float*)d_in[0];
    const int*   ei    = (const int*)d_in[1];
    const float* ea    = (const float*)d_in[2];
    const int*   batch = (const int*)d_in[3];
    const float* W_ne  = (const float*)d_in[4];
    const float* b_ne  = (const float*)d_in[5];
    const float* W_ee  = (const float*)d_in[6];
    const float* b_ee  = (const float*)d_in[7];
    const float* W_l3  = (const float*)d_in[8];
    const float* b_l3  = (const float*)d_in[9];
    const float *Wl[3], *asl[3], *adl[3], *Wel[3], *ael[3], *bbl[3];
    for (int l = 0; l < 3; ++l) {
        Wl[l]  = (const float*)d_in[10 + 6 * l];
        asl[l] = (const float*)d_in[11 + 6 * l];
        adl[l] = (const float*)d_in[12 + 6 * l];
        Wel[l] = (const float*)d_in[13 + 6 * l];
        ael[l] = (const float*)d_in[14 + 6 * l];
        bbl[l] = (const float*)d_in[15 + 6 * l];
    }

    const int n  = in_sizes[3];        // 100000
    const int e  = in_sizes[2] / 3;    // 1600000
    const int ep = e + n;
    const int* ei0 = ei;
    const int* ei1 = ei + e;
    const int nbuck = (n + 255) >> NBUCK_SHIFT;   // 391

    char* w = (char*)d_ws;
    size_t off = 0;
    auto alloc = [&](size_t b) { size_t o = off; off = (off + b + 255) & ~(size_t)255; return o; };
    float*        x0      = (float*)(w + alloc((size_t)n * 16 * 4));
    float*        x1      = (float*)(w + alloc((size_t)n * 32 * 4));
    float*        x2      = (float*)(w + alloc((size_t)n * 32 * 4));
    float*        x3      = (float*)(w + alloc((size_t)n * 32 * 4));
    unsigned int* h2      = (unsigned int*)(w + alloc((size_t)n * 16 * 4));
    float*        asrc    = (float*)(w + alloc((size_t)n * 4));
    float*        adst    = (float*)(w + alloc((size_t)n * 4));
    uint2*        st      = (uint2*)(w + alloc((size_t)ep * 8));
    uint2*        rec     = (uint2*)(w + alloc((size_t)ep * 8));
    int*          rp      = (int*)(w + alloc((size_t)(n + 1) * 4));
    int*          bcnt    = (int*)(w + alloc(NBUCK_MAX * 4));
    int*          bbase   = (int*)(w + alloc((NBUCK_MAX + 1) * 4));
    int*          bcur    = (int*)(w + alloc(NBUCK_MAX * 4));
    float2*       partial = (float2*)(w + alloc((size_t)8192 * 8));
    float*        consts  = (float*)(w + alloc(256));
    int*          bounds  = (int*)(w + alloc(129 * 4));
    float*        gsum    = (float*)(w + alloc((size_t)128 * 32 * 4));

    hipMemsetAsync(bcnt, 0, NBUCK_MAX * 4, stream);
    hipMemsetAsync(gsum, 0, (size_t)128 * 32 * 4, stream);

    int e4 = e >> 2;
    int nbe = (e4 + 255) / 256;
    int nw  = nbe * 4;
    int nbs = (ep + 4095) / 4096;

    k_node_enc<<<(n * 16 + 255) / 256, 256, 0, stream>>>(nf, W_ne, b_ne, x0, n);
    k_colsum<<<nbe, 256, 0, stream>>>((const float4*)ea, W_ee, b_ee, partial, e);
    k_consts<<<1, 256, 0, stream>>>(Wel[0], ael[0], Wel[1], ael[1], Wel[2], ael[2],
                                    partial, nw, 1.0f / (float)e, consts);
    k_hist<<<nbs, 256, 0, stream>>>(ei1, bcnt, e, ep);
    k_bbase<<<1, 512, 0, stream>>>(bcnt, bbase, bcur, nbuck, ep, rp, n);
    k_binB<<<nbs, 256, 0, stream>>>(ei0, ei1, ea, W_ee, b_ee, consts, bcur, st, e, ep);
    k_binC<<<nbuck, 512, 0, stream>>>(st, bbase, rp, rec, n);
    k_bounds<<<1, 256, 0, stream>>>(batch, bounds, n, 128);

    const float* xin = x0;
    float* xo[3] = {x1, x2, x3};
    for (int l = 0; l < 3; ++l) {
        if (l == 0)
            k_hproj<16><<<(n + 7) / 8, 256, 0, stream>>>(xin, Wl[l], asl[l], adl[l],
                                                         h2, asrc, adst, n);
        else
            k_hproj<32><<<(n + 7) / 8, 256, 0, stream>>>(xin, Wl[l], asl[l], adl[l],
                                                         h2, asrc, adst, n);
        k_agg<<<(n + 7) / 8, 256, 0, stream>>>(rp, rec, asrc, adst, consts,
                                               h2, bbl[l], xo[l], n, l);
        xin = xo[l];
    }
    k_dot<<<(n + 7) / 8, 256, 0, stream>>>(x1, x2, x3, batch, W_l3, gsum, n);
    k_out<<<1, 128, 0, stream>>>(gsum, bounds, b_l3, (float*)d_out, 128);
}

// Round 9
// 384.328 us; speedup vs baseline: 1.1034x; 1.0870x over previous
//
#include <hip/hip_runtime.h>
#include <hip/hip_fp16.h>

// ---------------------------------------------------------------------------
// 3-layer GAT (heads=1) forward. N=100000, E=1600000, Ep=E+N, G=128,
// ND=16, ED=2, H=32.
// R9: dispatch-count consolidation + k_agg regroup.
//  - k_pre: node_enc | colsum | hist | bounds fused (grid-partitioned).
//  - k_mid: consts | bbase fused (2 blocks).
//  - k_agg: 16-lane groups (lane = half2 word = 2 cols, float2 acc);
//    layer 2 fuses the readout dot (x3 never hits memory; k_dot gone).
//  - 17 -> 11 dispatches/call.
// Carried: LDS bucket sort (R6), fp16 h (R8), NT rec loads (R7).
// ---------------------------------------------------------------------------

#define NBUCK_SHIFT 8
#define NBUCK_MAX 512
#define CAP 6144   // max staged edges per 256-node bucket (mean ~4350, max ~4650)

// ---- fused preprocessing: [node_enc | colsum | hist | bounds] -------------
__global__ void k_pre(const float* __restrict__ nf, const float* __restrict__ Wne,
                      const float* __restrict__ bne, float* __restrict__ x0,
                      const float4* __restrict__ ea4, const float* __restrict__ Wee,
                      const float* __restrict__ bee, float2* __restrict__ partial,
                      const int* __restrict__ ei1, int* __restrict__ bucket_cnt,
                      const int* __restrict__ batch, int* __restrict__ bounds,
                      int n, int e, int ep, int nbNE, int nbCS, int nbH) {
    int b = blockIdx.x, t = threadIdx.x;
    if (b < nbNE) {
        // node encoder: x0 = nf @ W_ne + b_ne
        int gid = b * 256 + t;
        if (gid >= n * 16) return;
        int node = gid >> 4, j = gid & 15;
        const float* xr = nf + node * 9;
        float acc = bne[j];
#pragma unroll
        for (int k = 0; k < 9; ++k) acc += xr[k] * Wne[k * 16 + j];
        x0[gid] = acc;
        return;
    }
    b -= nbNE;
    if (b < nbCS) {
        // ef column sums (self-loop mean fill), 4 edges/thread, no atomics
        int tid = b * 256 + t;
        int e4 = e >> 2;
        float s0 = 0.f, s1 = 0.f;
        if (tid < e4) {
            float4 q0 = ea4[tid * 3], q1 = ea4[tid * 3 + 1], q2 = ea4[tid * 3 + 2];
            float a = q0.x + q0.w + q1.z + q2.y;
            float b2 = q0.y + q1.x + q1.w + q2.z;
            float c = q0.z + q1.y + q2.x + q2.w;
            s0 = a * Wee[0] + b2 * Wee[2] + c * Wee[4] + 4.f * bee[0];
            s1 = a * Wee[1] + b2 * Wee[3] + c * Wee[5] + 4.f * bee[1];
        }
#pragma unroll
        for (int off = 32; off > 0; off >>= 1) {
            s0 += __shfl_xor(s0, off, 64);
            s1 += __shfl_xor(s1, off, 64);
        }
        if ((t & 63) == 0)
            partial[(b << 2) + (t >> 6)] = make_float2(s0, s1);
        return;
    }
    b -= nbCS;
    if (b < nbH) {
        // bucket histogram (bucket = dst>>8), 4096 edges/block
        __shared__ int lh[NBUCK_MAX];
        lh[t] = 0; lh[t + 256] = 0;
        __syncthreads();
        int base = b * 4096;
#pragma unroll
        for (int i = 0; i < 16; ++i) {
            int gid = base + i * 256 + t;
            if (gid < ep) {
                int d = (gid < e) ? ei1[gid] : gid - e;
                atomicAdd(&lh[d >> NBUCK_SHIFT], 1);
            }
        }
        __syncthreads();
        if (lh[t]) atomicAdd(&bucket_cnt[t], lh[t]);
        if (lh[t + 256]) atomicAdd(&bucket_cnt[t + 256], lh[t + 256]);
        return;
    }
    // graph boundaries by binary search (batch sorted)
    for (int g = t; g <= 128; g += 256) {
        if (g == 128) { bounds[128] = n; continue; }
        int lo = 0, hi = n;
        while (lo < hi) {
            int mid = (lo + hi) >> 1;
            if (batch[mid] < g) lo = mid + 1; else hi = mid;
        }
        bounds[g] = lo;
    }
}

// ---- fused mid: block 0 = consts reduce, block 1 = bucket-base scan -------
__global__ void __launch_bounds__(512)
k_mid(const float* __restrict__ We0, const float* __restrict__ ae0,
      const float* __restrict__ We1, const float* __restrict__ ae1,
      const float* __restrict__ We2, const float* __restrict__ ae2,
      const float2* __restrict__ partial, int nw, float einv,
      float* __restrict__ consts,
      const int* __restrict__ bucket_cnt, int* __restrict__ bucket_base,
      int* __restrict__ bcursor, int nbuck, int ep, int* __restrict__ rp, int n) {
    int t = threadIdx.x;
    if (blockIdx.x == 0) {
        __shared__ float r0[512], r1[512];
        float m0 = 0.f, m1 = 0.f;
        for (int i = t; i < nw; i += 512) {
            float2 v = partial[i];
            m0 += v.x; m1 += v.y;
        }
        r0[t] = m0; r1[t] = m1;
        __syncthreads();
        for (int o = 256; o > 0; o >>= 1) {
            if (t < o) { r0[t] += r0[t + o]; r1[t] += r1[t + o]; }
            __syncthreads();
        }
        if (t == 0) {
            consts[12] = r0[0] * einv;
            consts[13] = r1[0] * einv;
            const float* We[3] = {We0, We1, We2};
            const float* ae[3] = {ae0, ae1, ae2};
            for (int l = 0; l < 3; ++l) {
                float c0 = 0.f, c1 = 0.f;
                for (int j = 0; j < 32; ++j) {
                    c0 += We[l][j] * ae[l][j];
                    c1 += We[l][32 + j] * ae[l][j];
                }
                consts[l * 2 + 0] = c0;
                consts[l * 2 + 1] = c1;
            }
        }
    } else {
        __shared__ int s[512];
        int v = (t < nbuck) ? bucket_cnt[t] : 0;
        s[t] = v;
        __syncthreads();
        for (int o = 1; o < 512; o <<= 1) {
            int x = (t >= o) ? s[t - o] : 0;
            __syncthreads();
            s[t] += x;
            __syncthreads();
        }
        int ex = s[t] - v;
        if (t < nbuck) { bucket_base[t] = ex; bcursor[t] = ex; }
        if (t == 0) { bucket_base[nbuck] = ep; rp[n] = ep; }
    }
}

// Phase B: stage edges grouped by bucket; one 8B uint2 {src<<8|dloc, half2}
// per edge; per-(block,bucket) run reservation keeps stores line-local.
__global__ void k_binB(const int* __restrict__ ei0, const int* __restrict__ ei1,
                       const float* __restrict__ ea, const float* __restrict__ We,
                       const float* __restrict__ be, const float* __restrict__ consts,
                       int* __restrict__ bcursor, uint2* __restrict__ st, int e, int ep) {
    __shared__ int lh[NBUCK_MAX], lcur[NBUCK_MAX];
    int t = threadIdx.x;
    lh[t] = 0; lh[t + 256] = 0;
    __syncthreads();
    int base = blockIdx.x * 4096;
    unsigned int sd[16], fh[16];
    int bk[16];
    float w00 = We[0], w10 = We[2], w20 = We[4];
    float w01 = We[1], w11 = We[3], w21 = We[5];
    float b0 = be[0], b1 = be[1];
#pragma unroll
    for (int i = 0; i < 16; ++i) {
        int gid = base + i * 256 + t;
        bk[i] = -1;
        if (gid < ep) {
            int s, d; float f0, f1;
            if (gid < e) {
                s = ei0[gid]; d = ei1[gid];
                const float* r = ea + (size_t)gid * 3;
                float a0 = r[0], a1 = r[1], a2 = r[2];
                f0 = a0 * w00 + a1 * w10 + a2 * w20 + b0;
                f1 = a0 * w01 + a1 * w11 + a2 * w21 + b1;
            } else {
                s = d = gid - e;
                f0 = consts[12]; f1 = consts[13];
            }
            bk[i] = d >> NBUCK_SHIFT;
            sd[i] = ((unsigned int)s << NBUCK_SHIFT) | (unsigned int)(d & 255);
            __half2 hh = __floats2half2_rn(f0, f1);
            fh[i] = *reinterpret_cast<unsigned int*>(&hh);
            atomicAdd(&lh[bk[i]], 1);
        }
    }
    __syncthreads();
    if (lh[t] > 0) lcur[t] = atomicAdd(&bcursor[t], lh[t]);
    if (lh[t + 256] > 0) lcur[t + 256] = atomicAdd(&bcursor[t + 256], lh[t + 256]);
    __syncthreads();
#pragma unroll
    for (int i = 0; i < 16; ++i) {
        if (bk[i] >= 0) {
            int pos = atomicAdd(&lcur[bk[i]], 1);
            st[pos] = make_uint2(sd[i], fh[i]);
        }
    }
}

// Phase C: one 512-thread block per bucket. LDS node-hist + scan -> rp
// coalesced; scatter into LDS-sorted buffer; stream out coalesced.
__global__ void __launch_bounds__(512)
k_binC(const uint2* __restrict__ st, const int* __restrict__ bucket_base,
       int* __restrict__ rp, uint2* __restrict__ rec, int n) {
    __shared__ int nh[256], ns[256];
    __shared__ uint2 rs[CAP];
    int k = blockIdx.x, t = threadIdx.x;
    int s0 = bucket_base[k], s1 = bucket_base[k + 1];
    int cnt = s1 - s0;
    if (t < 256) nh[t] = 0;
    __syncthreads();
    for (int i = s0 + t; i < s1; i += 512)
        atomicAdd(&nh[st[i].x & 255], 1);
    __syncthreads();
    if (t < 256) ns[t] = nh[t];
    __syncthreads();
    for (int o = 1; o < 256; o <<= 1) {
        int add = 0;
        if (t < 256 && t >= o) add = ns[t - o];
        __syncthreads();
        if (t < 256) ns[t] += add;
        __syncthreads();
    }
    int node0 = k << NBUCK_SHIFT;
    if (t < 256) {
        int startl = ns[t] - nh[t];      // exclusive, bucket-local
        if (node0 + t < n) rp[node0 + t] = s0 + startl;
        nh[t] = startl;                  // becomes local cursor
    }
    __syncthreads();
    for (int i = s0 + t; i < s1; i += 512) {
        uint2 v = st[i];
        int pos = atomicAdd(&nh[v.x & 255], 1);
        uint2 r = make_uint2(v.x >> NBUCK_SHIFT, v.y);
        if (pos < CAP) rs[pos] = r;
        else rec[s0 + pos] = r;          // overflow fallback (never in practice)
    }
    __syncthreads();
    int m = cnt < CAP ? cnt : CAP;
    for (int i = t; i < m; i += 512)
        rec[s0 + i] = rs[i];
}

// h stored packed half2: h2[node*16 + (j>>1)] holds cols (2k, 2k+1).
template <int K>
__global__ void k_hproj(const float* __restrict__ x, const float* __restrict__ W,
                        const float* __restrict__ as_, const float* __restrict__ ad_,
                        unsigned int* __restrict__ h2, float* __restrict__ asrc,
                        float* __restrict__ adst, int n) {
    __shared__ float sW[K * 32];
    for (int i = threadIdx.x; i < K * 32; i += 256) sW[i] = W[i];
    __syncthreads();
    int node = blockIdx.x * 8 + (threadIdx.x >> 5);
    int j = threadIdx.x & 31;
    if (node >= n) return;
    const float* xr = x + (size_t)node * K;
    float acc = 0.f;
#pragma unroll
    for (int k = 0; k < K; ++k) acc += xr[k] * sW[k * 32 + j];
    float accp = __shfl_down(acc, 1, 32);
    if ((j & 1) == 0) {
        __half2 hh = __floats2half2_rn(acc, accp);
        h2[(size_t)node * 16 + (j >> 1)] = *reinterpret_cast<unsigned int*>(&hh);
    }
    float r1 = acc * as_[j], r2 = acc * ad_[j];
    for (int off = 16; off > 0; off >>= 1) {
        r1 += __shfl_xor(r1, off, 32);
        r2 += __shfl_xor(r2, off, 32);
    }
    if (j == 0) { asrc[node] = r1; adst[node] = r2; }
}

__device__ __forceinline__ float2 h2f2(unsigned int hw) {
    __half2 hh = *reinterpret_cast<__half2*>(&hw);
    return make_float2(__low2float(hh), __high2float(hh));
}

// Fused edge-softmax + aggregation. 16-lane group per dst node: lane w owns
// packed word w (cols 2w,2w+1), float2 accumulator. One wave = 4 nodes.
// LAST: fuses the commuted readout dot (x3 stays in registers).
template <bool LAST>
__global__ void k_agg(const int* __restrict__ rp, const uint2* __restrict__ rec,
                      const float* __restrict__ asrc, const float* __restrict__ adst,
                      const float* __restrict__ consts, const unsigned int* __restrict__ h2,
                      const float* __restrict__ bb, float* __restrict__ xout,
                      const float* __restrict__ x1, const float* __restrict__ x2,
                      const int* __restrict__ batch, const float* __restrict__ Wl3,
                      float* __restrict__ gsum, int n, int layer) {
    int node = blockIdx.x * 16 + (threadIdx.x >> 4);
    int w = threadIdx.x & 15;
    if (node >= n) return;
    float c0 = consts[layer * 2], c1 = consts[layer * 2 + 1];
    int r0 = rp[node], r1 = rp[node + 1];
    float adn = adst[node];
    float2 acc = make_float2(0.f, 0.f);
    float psum = 0.f;
    for (int c = r0; c < r1; c += 16) {
        int i = c + w;
        float pe = 0.f; int s = 0;
        if (i < r1) {
            unsigned long long rv = __builtin_nontemporal_load(
                reinterpret_cast<const unsigned long long*>(rec + i));
            s = (int)(unsigned int)(rv & 0xffffffffull);
            unsigned int fv = (unsigned int)(rv >> 32);
            __half2 hh = *reinterpret_cast<__half2*>(&fv);
            float lg = asrc[s] + adn + __low2float(hh) * c0 + __high2float(hh) * c1;
            lg = lg > 0.f ? lg : 0.2f * lg;
            pe = __expf(lg);
        }
        psum += pe;
        int cnt = min(16, r1 - c);
        int t = 0;
        for (; t + 8 <= cnt; t += 8) {
            int s0 = __shfl(s, t, 16),     s1 = __shfl(s, t + 1, 16);
            int s2 = __shfl(s, t + 2, 16), s3 = __shfl(s, t + 3, 16);
            int s4 = __shfl(s, t + 4, 16), s5 = __shfl(s, t + 5, 16);
            int s6 = __shfl(s, t + 6, 16), s7 = __shfl(s, t + 7, 16);
            float p0 = __shfl(pe, t, 16),     p1 = __shfl(pe, t + 1, 16);
            float p2 = __shfl(pe, t + 2, 16), p3 = __shfl(pe, t + 3, 16);
            float p4 = __shfl(pe, t + 4, 16), p5 = __shfl(pe, t + 5, 16);
            float p6 = __shfl(pe, t + 6, 16), p7 = __shfl(pe, t + 7, 16);
            unsigned int g0 = h2[(size_t)s0 * 16 + w];
            unsigned int g1 = h2[(size_t)s1 * 16 + w];
            unsigned int g2 = h2[(size_t)s2 * 16 + w];
            unsigned int g3 = h2[(size_t)s3 * 16 + w];
            unsigned int g4 = h2[(size_t)s4 * 16 + w];
            unsigned int g5 = h2[(size_t)s5 * 16 + w];
            unsigned int g6 = h2[(size_t)s6 * 16 + w];
            unsigned int g7 = h2[(size_t)s7 * 16 + w];
            float2 f0 = h2f2(g0), f1 = h2f2(g1), f2 = h2f2(g2), f3 = h2f2(g3);
            float2 f4 = h2f2(g4), f5 = h2f2(g5), f6 = h2f2(g6), f7 = h2f2(g7);
            acc.x += p0 * f0.x; acc.y += p0 * f0.y;
            acc.x += p1 * f1.x; acc.y += p1 * f1.y;
            acc.x += p2 * f2.x; acc.y += p2 * f2.y;
            acc.x += p3 * f3.x; acc.y += p3 * f3.y;
            acc.x += p4 * f4.x; acc.y += p4 * f4.y;
            acc.x += p5 * f5.x; acc.y += p5 * f5.y;
            acc.x += p6 * f6.x; acc.y += p6 * f6.y;
            acc.x += p7 * f7.x; acc.y += p7 * f7.y;
        }
        for (; t + 4 <= cnt; t += 4) {
            int s0 = __shfl(s, t, 16),     s1 = __shfl(s, t + 1, 16);
            int s2 = __shfl(s, t + 2, 16), s3 = __shfl(s, t + 3, 16);
            float p0 = __shfl(pe, t, 16),     p1 = __shfl(pe, t + 1, 16);
            float p2 = __shfl(pe, t + 2, 16), p3 = __shfl(pe, t + 3, 16);
            unsigned int g0 = h2[(size_t)s0 * 16 + w];
            unsigned int g1 = h2[(size_t)s1 * 16 + w];
            unsigned int g2 = h2[(size_t)s2 * 16 + w];
            unsigned int g3 = h2[(size_t)s3 * 16 + w];
            float2 f0 = h2f2(g0), f1 = h2f2(g1), f2 = h2f2(g2), f3 = h2f2(g3);
            acc.x += p0 * f0.x; acc.y += p0 * f0.y;
            acc.x += p1 * f1.x; acc.y += p1 * f1.y;
            acc.x += p2 * f2.x; acc.y += p2 * f2.y;
            acc.x += p3 * f3.x; acc.y += p3 * f3.y;
        }
        for (; t < cnt; ++t) {
            int st2 = __shfl(s, t, 16);
            float pt = __shfl(pe, t, 16);
            float2 ft = h2f2(h2[(size_t)st2 * 16 + w]);
            acc.x += pt * ft.x; acc.y += pt * ft.y;
        }
    }
#pragma unroll
    for (int off = 8; off > 0; off >>= 1) psum += __shfl_xor(psum, off, 16);
    float inv = 1.f / (psum + 1e-16f);
    const float2* bb2 = reinterpret_cast<const float2*>(bb);
    float2 res = make_float2(acc.x * inv + bb2[w].x, acc.y * inv + bb2[w].y);
    if (!LAST) {
        reinterpret_cast<float2*>(xout)[(size_t)node * 16 + w] = res;
    } else {
        const float2* X1 = reinterpret_cast<const float2*>(x1);
        const float2* X2 = reinterpret_cast<const float2*>(x2);
        const float2* W3 = reinterpret_cast<const float2*>(Wl3);
        float2 a1 = X1[(size_t)node * 16 + w], a2 = X2[(size_t)node * 16 + w];
        float2 w1 = W3[w], w2 = W3[16 + w], w3 = W3[32 + w];
        float v = a1.x * w1.x + a1.y * w1.y + a2.x * w2.x + a2.y * w2.y
                + res.x * w3.x + res.y * w3.y;
#pragma unroll
        for (int off = 8; off > 0; off >>= 1) v += __shfl_xor(v, off, 16);
        if (w == 0) atomicAdd(gsum + (size_t)batch[node] * 32 + (blockIdx.x & 31), v);
    }
}

__global__ void k_out(const float* __restrict__ gsum, const int* __restrict__ bounds,
                      const float* __restrict__ bl3, float* __restrict__ out, int g) {
    int t = threadIdx.x;
    if (t >= g) return;
    float acc = 0.f;
    for (int k = 0; k < 32; ++k) acc += gsum[(size_t)t * 32 + k];
    float cnt = (float)(bounds[t + 1] - bounds[t]);
    out[t] = acc / fmaxf(cnt, 1.f) + bl3[0];
}

extern "C" void kernel_launch(void* const* d_in, const int* in_sizes, int n_in,
                              void* d_out, int out_size, void* d_ws, size_t ws_size,
                              hipStream_t stream) {
    (void)n_in; (void)out_size; (void)ws_size;
    const float* nf    = (const float*)d_in[0];
    const int*   ei    = (const int*)d_in[1];
    const float* ea    = (const float*)d_in[2];
    const int*   batch = (const int*)d_in[3];
    const float* W_ne  = (const float*)d_in[4];
    const float* b_ne  = (const float*)d_in[5];
    const float* W_ee  = (const float*)d_in[6];
    const float* b_ee  = (const float*)d_in[7];
    const float* W_l3  = (const float*)d_in[8];
    const float* b_l3  = (const float*)d_in[9];
    const float *Wl[3], *asl[3], *adl[3], *Wel[3], *ael[3], *bbl[3];
    for (int l = 0; l < 3; ++l) {
        Wl[l]  = (const float*)d_in[10 + 6 * l];
        asl[l] = (const float*)d_in[11 + 6 * l];
        adl[l] = (const float*)d_in[12 + 6 * l];
        Wel[l] = (const float*)d_in[13 + 6 * l];
        ael[l] = (const float*)d_in[14 + 6 * l];
        bbl[l] = (const float*)d_in[15 + 6 * l];
    }

    const int n  = in_sizes[3];        // 100000
    const int e  = in_sizes[2] / 3;    // 1600000
    const int ep = e + n;
    const int* ei0 = ei;
    const int* ei1 = ei + e;
    const int nbuck = (n + 255) >> NBUCK_SHIFT;   // 391

    char* w = (char*)d_ws;
    size_t off = 0;
    auto alloc = [&](size_t b) { size_t o = off; off = (off + b + 255) & ~(size_t)255; return o; };
    float*        x0      = (float*)(w + alloc((size_t)n * 16 * 4));
    float*        x1      = (float*)(w + alloc((size_t)n * 32 * 4));
    float*        x2      = (float*)(w + alloc((size_t)n * 32 * 4));
    unsigned int* h2      = (unsigned int*)(w + alloc((size_t)n * 16 * 4));
    float*        asrc    = (float*)(w + alloc((size_t)n * 4));
    float*        adst    = (float*)(w + alloc((size_t)n * 4));
    uint2*        st      = (uint2*)(w + alloc((size_t)ep * 8));
    uint2*        rec     = (uint2*)(w + alloc((size_t)ep * 8));
    int*          rp      = (int*)(w + alloc((size_t)(n + 1) * 4));
    int*          bcnt    = (int*)(w + alloc(NBUCK_MAX * 4));
    int*          bbase   = (int*)(w + alloc((NBUCK_MAX + 1) * 4));
    int*          bcur    = (int*)(w + alloc(NBUCK_MAX * 4));
    float2*       partial = (float2*)(w + alloc((size_t)8192 * 8));
    float*        consts  = (float*)(w + alloc(256));
    int*          bounds  = (int*)(w + alloc(129 * 4));
    float*        gsum    = (float*)(w + alloc((size_t)128 * 32 * 4));

    hipMemsetAsync(bcnt, 0, NBUCK_MAX * 4, stream);
    hipMemsetAsync(gsum, 0, (size_t)128 * 32 * 4, stream);

    int e4   = e >> 2;
    int nbNE = (n * 16 + 255) / 256;     // 6250
    int nbCS = (e4 + 255) / 256;         // 1563
    int nbH  = (ep + 4095) / 4096;       // 416
    int nw   = nbCS * 4;

    k_pre<<<nbNE + nbCS + nbH + 1, 256, 0, stream>>>(
        nf, W_ne, b_ne, x0, (const float4*)ea, W_ee, b_ee, partial,
        ei1, bcnt, batch, bounds, n, e, ep, nbNE, nbCS, nbH);
    k_mid<<<2, 512, 0, stream>>>(Wel[0], ael[0], Wel[1], ael[1], Wel[2], ael[2],
                                 partial, nw, 1.0f / (float)e, consts,
                                 bcnt, bbase, bcur, nbuck, ep, rp, n);
    k_binB<<<nbH, 256, 0, stream>>>(ei0, ei1, ea, W_ee, b_ee, consts, bcur, st, e, ep);
    k_binC<<<nbuck, 512, 0, stream>>>(st, bbase, rp, rec, n);

    const float* xin = x0;
    float* xo[2] = {x1, x2};
    for (int l = 0; l < 3; ++l) {
        if (l == 0)
            k_hproj<16><<<(n + 7) / 8, 256, 0, stream>>>(xin, Wl[l], asl[l], adl[l],
                                                         h2, asrc, adst, n);
        else
            k_hproj<32><<<(n + 7) / 8, 256, 0, stream>>>(xin, Wl[l], asl[l], adl[l],
                                                         h2, asrc, adst, n);
        if (l < 2) {
            k_agg<false><<<(n + 15) / 16, 256, 0, stream>>>(
                rp, rec, asrc, adst, consts, h2, bbl[l], xo[l],
                nullptr, nullptr, nullptr, nullptr, nullptr, n, l);
            xin = xo[l];
        } else {
            k_agg<true><<<(n + 15) / 16, 256, 0, stream>>>(
                rp, rec, asrc, adst, consts, h2, bbl[l], nullptr,
                x1, x2, batch, W_l3, gsum, n, l);
        }
    }
    k_out<<<1, 128, 0, stream>>>(gsum, bounds, b_l3, (float*)d_out, 128);
}